// Round 13
// baseline (75.223 us; speedup 1.0000x reference)
//
#include <hip/hip_runtime.h>
#include <hip/hip_bf16.h>
#include <math.h>

#define BB 4
#define LL 1024
#define EE 1024
#define HH 16
#define DD 64
#define VROWS 80     // V padded: 64 data rows + ones-row(64) + 15 zero rows
#define NCH 8
#define CHROWS 128   // LL / NCH
#define K2C 0.04508422002777998f   // log2(e)/32, pre-folded into Q

typedef __attribute__((ext_vector_type(8))) short short8;
typedef __attribute__((ext_vector_type(4))) float f32x4;
typedef __attribute__((ext_vector_type(4))) int int4v;

static __device__ __forceinline__ unsigned short bfbits(float x) {
    __hip_bfloat16 h = __float2bfloat16(x);
    return *(unsigned short*)&h;
}

#define CVTPK(dst, lo_, hi_) \
    asm("v_cvt_pk_bf16_f32 %0, %1, %2" : "=v"(dst) : "v"(lo_), "v"(hi_))

// ---------------------------------------------------------------------------
// Kernel 1 (fused prep): block-range dispatch
//   [0, 4096)    : grouped 3x3 conv -> bf16 qcb[bh][l][d], PRE-SCALED by K2C
//   [4096, 5120) : value linear -> PERMUTED transposed bf16 vt[bh][80][l'],
//                  masked columns zeroed; row 64 = mask01 (permuted);
//                  rows 65..79 = 0.
//   [5120, 5632) : keys column-softmax chunk partials
// ---------------------------------------------------------------------------
__global__ __launch_bounds__(256) void prep_kernel(
    const float* __restrict__ query,
    const float* __restrict__ conv_w,
    const float* __restrict__ conv_b,
    const float* __restrict__ values,
    const float* __restrict__ Wv,
    const float* __restrict__ keys,
    const int* __restrict__ bern,
    const int* __restrict__ pad,
    const int* __restrict__ cau,
    __hip_bfloat16* __restrict__ qcb,
    __hip_bfloat16* __restrict__ vt,
    float* __restrict__ pmax,
    float* __restrict__ psum) {
    __shared__ __align__(16) char SM[34304];
    int tid = threadIdx.x;
    int bid = blockIdx.x;

    if (bid < 4096) {
        // ---------------- conv (Q pre-scaled by K2C) ----------------
        int d = tid & 63;
        int lr = tid >> 6;
        int l0 = (bid & (LL / 4 - 1)) << 2;
        int bh = bid >> 8;
        int h = bh & (HH - 1);
        int b = bh >> 4;
        int l = l0 + lr;

        const float* w = conv_w + h * 9;
        float acc = conv_b[h];
        const float* qin = query + ((size_t)b * LL) * EE + h * DD;
        #pragma unroll
        for (int i = 0; i < 3; ++i) {
            int li = l + i - 1;
            if (li < 0 || li >= LL) continue;
            #pragma unroll
            for (int j = 0; j < 3; ++j) {
                int dj = d + j - 1;
                if (dj < 0 || dj >= DD) continue;
                acc += w[i * 3 + j] * qin[(size_t)li * EE + dj];
            }
        }
        qcb[((size_t)bh * LL + l) * DD + d] = __float2bfloat16(acc * K2C);
    } else if (bid < 5120) {
        // ---------------- vlin (masked, permuted, +ones-row) ----------------
        float (*WvS)[65] = (float(*)[65])SM;            // 16640 B
        float (*vs)[68]  = (float(*)[68])(SM + 16640);  // 17408 B
        float* mS = (float*)(SM + 34048);               // 64 floats
        int tile = bid - 4096;
        int lt = tile & 15;
        int bh = tile >> 4;
        int h = bh & (HH - 1);
        int b = bh >> 4;
        int l0 = lt * 64;

        if (tid < 64) {
            int l = l0 + tid;
            mS[tid] = ((pad[b * LL + l] != 0) & (cau[b * LL + l] != 0)) ? 0.f : 1.f;
        }
        for (int idx = tid; idx < 64 * 64; idx += 256)
            WvS[idx >> 6][idx & 63] = Wv[idx];
        const float* vin = values + ((size_t)b * LL + l0) * EE + h * DD;
        for (int idx = tid; idx < 1024; idx += 256) {
            int r = idx >> 4;
            int c4 = (idx & 15) << 2;
            *(float4*)&vs[r][c4] = *(const float4*)&vin[(size_t)r * EE + c4];
        }
        __syncthreads();

        int d = tid & 63;
        int r0 = (tid >> 6) * 16;
        float acc[16];
        #pragma unroll
        for (int r = 0; r < 16; ++r) acc[r] = 0.f;
        for (int k = 0; k < 64; ++k) {
            float wv = WvS[d][k];
            #pragma unroll
            for (int r = 0; r < 16; ++r) acc[r] += vs[r0 + r][k] * wv;
        }
        #pragma unroll
        for (int r = 0; r < 16; ++r) acc[r] *= mS[r0 + r];   // zero masked columns
        union { unsigned short us[16]; uint2 u2[4]; } pk;
        #pragma unroll
        for (int r = 0; r < 16; ++r) pk.us[r] = bfbits(acc[r]);
        // permuted write: source l0+16a+4g2+m -> l0 + 32(a>>1) + 4(a&1) + 8g2 + m
        int a = tid >> 6;
        int C32 = (a >> 1) << 5;
        int h4 = a & 1;
        __hip_bfloat16* vo = vt + ((size_t)bh * VROWS + d) * LL + l0 + C32 + 4 * h4;
        #pragma unroll
        for (int g2 = 0; g2 < 4; ++g2)
            *(uint2*)&vo[8 * g2] = pk.u2[g2];

        // ones-row (row 64), same permutation; rows 65..79 zero
        if (tid < 64) {
            int aa = tid >> 4, g2 = (tid >> 2) & 3, m = tid & 3;
            int dst = l0 + 32 * (aa >> 1) + 4 * (aa & 1) + 8 * g2 + m;
            vt[((size_t)bh * VROWS + 64) * LL + dst] = __float2bfloat16(mS[tid]);
        }
        for (int idx = tid; idx < 15 * 64; idx += 256) {
            int rr = idx >> 6, l = idx & 63;
            vt[((size_t)bh * VROWS + 65 + rr) * LL + l0 + l] = __float2bfloat16(0.f);
        }
    } else {
        // ---------------- ksm_partial ----------------
        float (*sm)[64] = (float(*)[64])SM;
        float (*ss)[64] = (float(*)[64])(SM + 1024);
        int blk = bid - 5120;
        int d = tid & 63;
        int seg = tid >> 6;
        int ch = blk & (NCH - 1);
        int bh = blk >> 3;
        int h = bh & (HH - 1);
        int b = bh >> 4;
        int r0 = ch * CHROWS + seg * 32;

        const float* kin = keys + ((size_t)b * LL + r0) * EE + h * DD + d;
        const int* bm = bern + (size_t)bh * LL + r0;

        float v[32];
        #pragma unroll
        for (int i = 0; i < 32; ++i) v[i] = kin[(size_t)i * EE];
        float m = -INFINITY;
        #pragma unroll
        for (int i = 0; i < 32; ++i)
            if (bm[i]) m = fmaxf(m, v[i]);
        float s = 0.f;
        #pragma unroll
        for (int i = 0; i < 32; ++i)
            if (bm[i]) s += __expf(v[i] - m);

        sm[seg][d] = m;
        ss[seg][d] = s;
        __syncthreads();
        if (seg == 0) {
            float M = sm[0][d];
            #pragma unroll
            for (int t = 1; t < 4; ++t) M = fmaxf(M, sm[t][d]);
            float S = 0.f;
            if (M > -INFINITY) {
                #pragma unroll
                for (int t = 0; t < 4; ++t)
                    if (sm[t][d] > -INFINITY) S += ss[t][d] * __expf(sm[t][d] - M);
            }
            pmax[(size_t)blk * 64 + d] = M;
            psum[(size_t)blk * 64 + d] = S;
        }
    }
}

// ---------------------------------------------------------------------------
// Kernel 2: combine chunk partials; normalize chunk; write bf16 ksb.
// ---------------------------------------------------------------------------
__global__ __launch_bounds__(256) void ksm_final_kernel(
    const float* __restrict__ keys,
    const int* __restrict__ bern,
    const float* __restrict__ pmax,
    const float* __restrict__ psum,
    __hip_bfloat16* __restrict__ ksb) {
    int tid = threadIdx.x;
    int d = tid & 63;
    int seg = tid >> 6;
    int blk = blockIdx.x;
    int ch = blk & (NCH - 1);
    int bh = blk >> 3;
    int h = bh & (HH - 1);
    int b = bh >> 4;
    int r0 = ch * CHROWS + seg * 32;

    const float* pm = pmax + (size_t)bh * NCH * 64;
    const float* ps = psum + (size_t)bh * NCH * 64;
    float M = -INFINITY;
    #pragma unroll
    for (int c = 0; c < NCH; ++c) M = fmaxf(M, pm[c * 64 + d]);
    float S = 0.f;
    #pragma unroll
    for (int c = 0; c < NCH; ++c) {
        float mi = pm[c * 64 + d];
        if (mi > -INFINITY) S += ps[c * 64 + d] * __expf(mi - M);
    }
    float inv = 1.f / S;

    const float* kin = keys + ((size_t)b * LL + r0) * EE + h * DD + d;
    const int* bm = bern + (size_t)bh * LL + r0;
    __hip_bfloat16* kout = ksb + ((size_t)bh * LL + r0) * DD + d;
    #pragma unroll
    for (int i = 0; i < 32; ++i) {
        float val = bm[i] ? __expf(kin[(size_t)i * EE] - M) * inv : 0.f;
        kout[(size_t)i * DD] = __float2bfloat16(val);
    }
}

// ---------------------------------------------------------------------------
// Kernel 3: swapped-QK^T flash attention, 16x16x32 MFMA, fully-folded softmax,
// 32 q-rows/wave (two Q/O register sets SHARING each K/V fragment read —
// halves LDS-read traffic per q). 4 waves x 32q = 128 q/block; 512 blocks.
// ---------------------------------------------------------------------------
__global__ __launch_bounds__(256) void attn_mfma_kernel(
    const __hip_bfloat16* __restrict__ qcb,
    const __hip_bfloat16* __restrict__ ksb,
    const __hip_bfloat16* __restrict__ vtb,
    float* __restrict__ out) {
    __shared__ __align__(16) short KsS[2][4096];   // 16 KB (64x64)
    __shared__ __align__(16) short VtS[2][5120];   // 20 KB (80x64)

    int tid = threadIdx.x;
    int lane = tid & 63;
    int w = tid >> 6;                  // 4 waves
    int q15 = lane & 15;
    int g = (lane >> 4) & 3;

    // XCD swizzle: 512 blocks; 64 consecutive swz per XCD -> 8 bh per L2
    int bid = blockIdx.x;
    int swz = (bid & 7) * 64 + (bid >> 3);
    int bh = swz >> 3;
    int qb = swz & 7;
    int b = bh >> 4;
    int h = bh & 15;
    int q0w = qb * 128 + w * 32;

    // staging geometry: rows (tid>>3), 8 chunks of 8 bf16, XOR-swizzled source
    int srow = tid >> 3;
    int sch = tid & 7;
    int ssw = (sch ^ (srow & 7)) << 3;
    const short* kg = (const short*)ksb + (size_t)bh * LL * DD + (size_t)srow * DD + ssw;
    const short* vg = (const short*)vtb + (size_t)bh * VROWS * LL + (size_t)srow * LL + ssw;
    const short* vgx = (const short*)vtb + (size_t)bh * VROWS * LL + (size_t)(64 + srow) * LL + ssw;

    // Q fragments, 2 q-sets (pre-scaled by K2C)
    short8 Qf[2][2];
    #pragma unroll
    for (int s = 0; s < 2; ++s) {
        const short* qrow = (const short*)qcb + ((size_t)bh * LL + q0w + 16 * s + q15) * DD + 8 * g;
        Qf[s][0] = *(const short8*)(qrow);
        Qf[s][1] = *(const short8*)(qrow + 32);
    }

    // prologue: tile 0
    #pragma unroll
    for (int it = 0; it < 2; ++it) {
        __builtin_amdgcn_global_load_lds(
            (const __attribute__((address_space(1))) void*)(kg + (size_t)(it * 32) * DD),
            (__attribute__((address_space(3))) void*)&KsS[0][(it * 4 + w) * 512], 16, 0, 0);
        __builtin_amdgcn_global_load_lds(
            (const __attribute__((address_space(1))) void*)(vg + (size_t)it * 32 * LL),
            (__attribute__((address_space(3))) void*)&VtS[0][(it * 4 + w) * 512], 16, 0, 0);
    }
    if (w < 2) {
        __builtin_amdgcn_global_load_lds(
            (const __attribute__((address_space(1))) void*)(vgx),
            (__attribute__((address_space(3))) void*)&VtS[0][4096 + w * 512], 16, 0, 0);
    }

    f32x4 O[2][4], O5[2];
    #pragma unroll
    for (int s = 0; s < 2; ++s) {
        #pragma unroll
        for (int u = 0; u < 4; ++u) O[s][u] = (f32x4){0.f, 0.f, 0.f, 0.f};
        O5[s] = (f32x4){0.f, 0.f, 0.f, 0.f};
    }

    for (int kt = 0; kt < 16; ++kt) {
        __syncthreads();   // tile kt ready; all waves done with other slot

        if (kt < 15) {
            int nb = (kt + 1) & 1;
            int k0n = (kt + 1) * 64;
            #pragma unroll
            for (int it = 0; it < 2; ++it) {
                __builtin_amdgcn_global_load_lds(
                    (const __attribute__((address_space(1))) void*)(kg + (size_t)(k0n + it * 32) * DD),
                    (__attribute__((address_space(3))) void*)&KsS[nb][(it * 4 + w) * 512], 16, 0, 0);
                __builtin_amdgcn_global_load_lds(
                    (const __attribute__((address_space(1))) void*)(vg + k0n + (size_t)it * 32 * LL),
                    (__attribute__((address_space(3))) void*)&VtS[nb][(it * 4 + w) * 512], 16, 0, 0);
            }
            if (w < 2) {
                __builtin_amdgcn_global_load_lds(
                    (const __attribute__((address_space(1))) void*)(vgx + k0n),
                    (__attribute__((address_space(3))) void*)&VtS[nb][4096 + w * 512], 16, 0, 0);
            }
        }

        int cb = kt & 1;
        const short* Kb = KsS[cb];
        const short* Vb = VtS[cb];
        int sw = q15 & 7;
        int off0 = (g ^ sw) << 3;
        int off1 = ((g + 4) ^ sw) << 3;

        // K fragments ONCE, shared by both q-sets
        short8 kf0[4], kf1[4];
        #pragma unroll
        for (int t = 0; t < 4; ++t) {
            kf0[t] = *(const short8*)&Kb[(16 * t + q15) * 64 + off0];
            kf1[t] = *(const short8*)&Kb[(16 * t + q15) * 64 + off1];
        }

        // S^T tiles for both q-sets
        f32x4 S[2][4];
        __builtin_amdgcn_s_setprio(1);
        #pragma unroll
        for (int s = 0; s < 2; ++s) {
            #pragma unroll
            for (int t = 0; t < 4; ++t) {
                f32x4 z = (f32x4){0.f, 0.f, 0.f, 0.f};
                z = __builtin_amdgcn_mfma_f32_16x16x32_bf16(kf0[t], Qf[s][0], z, 0, 0, 0);
                S[s][t] = __builtin_amdgcn_mfma_f32_16x16x32_bf16(kf1[t], Qf[s][1], z, 0, 0, 0);
            }
        }
        __builtin_amdgcn_s_setprio(0);

        // V fragments ONCE, shared by both q-sets
        short8 vfa[5], vfb[5];
        #pragma unroll
        for (int u = 0; u < 5; ++u) {
            vfa[u] = *(const short8*)&Vb[(16 * u + q15) * 64 + off0];
            vfb[u] = *(const short8*)&Vb[(16 * u + q15) * 64 + off1];
        }

        // softmax: pv = exp2(S); pack to lane-local B-fragments (permuted-V)
        union PW { int4v i4; short8 s8; } pw0[2], pw1[2];
        #pragma unroll
        for (int s = 0; s < 2; ++s) {
            float pv[4][4];
            #pragma unroll
            for (int t = 0; t < 4; ++t)
                #pragma unroll
                for (int r = 0; r < 4; ++r)
                    pv[t][r] = exp2f(S[s][t][r]);
            int d0, d1, d2, d3;
            CVTPK(d0, pv[0][0], pv[0][1]);
            CVTPK(d1, pv[0][2], pv[0][3]);
            CVTPK(d2, pv[1][0], pv[1][1]);
            CVTPK(d3, pv[1][2], pv[1][3]);
            pw0[s].i4 = (int4v){d0, d1, d2, d3};
            CVTPK(d0, pv[2][0], pv[2][1]);
            CVTPK(d1, pv[2][2], pv[2][3]);
            CVTPK(d2, pv[3][0], pv[3][1]);
            CVTPK(d3, pv[3][2], pv[3][3]);
            pw1[s].i4 = (int4v){d0, d1, d2, d3};
        }

        // O^T tiles + lsum tiles (ones-row)
        __builtin_amdgcn_s_setprio(1);
        #pragma unroll
        for (int s = 0; s < 2; ++s) {
            #pragma unroll
            for (int u = 0; u < 4; ++u) {
                O[s][u] = __builtin_amdgcn_mfma_f32_16x16x32_bf16(vfa[u], pw0[s].s8, O[s][u], 0, 0, 0);
                O[s][u] = __builtin_amdgcn_mfma_f32_16x16x32_bf16(vfb[u], pw1[s].s8, O[s][u], 0, 0, 0);
            }
            O5[s] = __builtin_amdgcn_mfma_f32_16x16x32_bf16(vfa[4], pw0[s].s8, O5[s], 0, 0, 0);
            O5[s] = __builtin_amdgcn_mfma_f32_16x16x32_bf16(vfb[4], pw1[s].s8, O5[s], 0, 0, 0);
        }
        __builtin_amdgcn_s_setprio(0);
    }

    // epilogue: lsum from O5 row 0 (lanes 0-15, reg 0), direct stores
    #pragma unroll
    for (int s = 0; s < 2; ++s) {
        float ls = __shfl(O5[s][0], q15, 64);
        float invl = 1.f / ls;
        float* gout = out + ((size_t)b * LL + q0w + 16 * s + q15) * EE + h * DD + 4 * g;
        #pragma unroll
        for (int u = 0; u < 4; ++u) {
            float4 vv = { O[s][u][0] * invl, O[s][u][1] * invl,
                          O[s][u][2] * invl, O[s][u][3] * invl };
            *(float4*)&gout[16 * u] = vv;
        }
    }
}

extern "C" void kernel_launch(void* const* d_in, const int* in_sizes, int n_in,
                              void* d_out, int out_size, void* d_ws, size_t ws_size,
                              hipStream_t stream) {
    const float* query = (const float*)d_in[0];
    const float* keys  = (const float*)d_in[1];
    const float* values = (const float*)d_in[2];
    const int* pad  = (const int*)d_in[3];
    const int* cau  = (const int*)d_in[4];
    const int* bern = (const int*)d_in[5];
    const float* conv_w = (const float*)d_in[6];
    const float* conv_b = (const float*)d_in[7];
    const float* Wv = (const float*)d_in[8];
    float* outp = (float*)d_out;

    const size_t per = (size_t)BB * HH * LL * DD;      // 4,194,304
    const size_t vper = (size_t)BB * HH * VROWS * LL;  // 5,242,880
    __hip_bfloat16* qcb = (__hip_bfloat16*)d_ws;
    __hip_bfloat16* ksb = qcb + per;
    __hip_bfloat16* vtb = ksb + per;
    float* pmax = (float*)(vtb + vper);
    float* psum = pmax + (size_t)BB * HH * NCH * 64;

    prep_kernel<<<5632, 256, 0, stream>>>(query, conv_w, conv_b, values, Wv,
                                          keys, bern, pad, cau,
                                          qcb, vtb, pmax, psum);
    ksm_final_kernel<<<BB * HH * NCH, 256, 0, stream>>>(keys, bern, pmax, psum, ksb);
    attn_mfma_kernel<<<BB * HH * 8, 256, 0, stream>>>(qcb, ksb, vtb, outp);
}